// Round 9
// baseline (5779.594 us; speedup 1.0000x reference)
//
#include <hip/hip_runtime.h>
#include <cstdint>
#include <cstddef>

// Exactness: prevent mul+add fusion everywhere (XLA ref uses unfused
// (dx*dx+dy*dy)+dz*dz). Explicit fmaf() calls in mlp_kernel are unaffected.
#pragma clang fp contract(off)

#define BATCH   4
#define NPTS    16384
#define NPOINT  1024
#define NSAMPLE 32
#define CIN     67          // 3 + 64 feature channels
#define R2f     0.04f       // (float)(0.2*0.2)

#define FPS_T   512         // 8 waves, one block per batch
#define NCELL   512         // 8x8x8 grid, one cell per thread
#define FPS_PAD 34          // (fallback kernel)

#define RPT16(M) M(0)M(1)M(2)M(3)M(4)M(5)M(6)M(7)M(8)M(9)M(10)M(11)M(12)M(13)M(14)M(15)

typedef float v2f __attribute__((ext_vector_type(2)));

// ---------------------------------------------------------------------------
// DPP-based argmax combine: max value, tie -> lowest index. VALU-pipe only.
// ---------------------------------------------------------------------------
template <int CTRL, int RMASK>
__device__ __forceinline__ void amax_dpp(float& v, int& i) {
  int nv = __builtin_amdgcn_update_dpp(__float_as_int(v), __float_as_int(v),
                                       CTRL, RMASK, 0xf, false);
  int ni = __builtin_amdgcn_update_dpp(i, i, CTRL, RMASK, 0xf, false);
  float fv = __int_as_float(nv);
  bool tk = (fv > v) || (fv == v && ni < i);
  v = tk ? fv : v;
  i = tk ? ni : i;
}

// float <-> order-preserving uint (for LDS atomic AABB min/max)
__device__ __forceinline__ unsigned f2o(float f) {
  unsigned u = __float_as_uint(f);
  return u ^ ((unsigned)((int)u >> 31) | 0x80000000u);
}
__device__ __forceinline__ float o2f(unsigned k) {
  unsigned u = (k & 0x80000000u) ? (k ^ 0x80000000u) : ~k;
  return __uint_as_float(u);
}

// ---------------------------------------------------------------------------
// Grid-pruned FPS (QuickFPS-style, exactness-safe). R7 post-mortem: ALL
// brute-force configs land at 1.9-2.1us/iter (64% active-CU VALU busy) --
// scanning 16K points/iter on 4 CUs is the structural floor; the scan must
// shrink. dd is pointwise monotone non-increasing, so a cell whose AABB
// satisfies lb2(centroid,AABB) > cellmax_dd + 1e-5 provably has min() as a
// no-op for EVERY point (fp-error of lb2/d2 <= ~2e-6 on coords in [0,1) --
// margin 1e-5 makes the skip conservative): skip the scan, reuse cached
// (max, argidx). dd evolution stays BIT-IDENTICAL to ref; within-cell tie ->
// lowest ORIGINAL index; cross-cell tie via DPP argmax (same as before).
// Prologue: bin points to 8x8x8 cells (LDS histogram + wave prefix-scan +
// scatter to ws as float4(x,y,z,idx)); exact AABBs via ordered-uint atomics.
// dd[16384] in LDS. Iter 0 rescans everything (cmax init 1e10). Thread t
// owns cell t; wave = spatial z-slab -> coherent skip/rescan.
// (R8: resubmit unchanged -- container infra failure, kernel audited
// hang-free: no spin loops, no cross-block sync, 84 KB LDS, bounded loops.)
// ---------------------------------------------------------------------------
__global__ void __launch_bounds__(FPS_T)
fps_grid(const float* __restrict__ xyz, float* __restrict__ out_newxyz,
         float4* __restrict__ ws)          // [BATCH][NPTS] sorted points
{
  __shared__ float    dd[NPTS];            // 64 KB, by sorted pos
  __shared__ int      cnt[NCELL];
  __shared__ int      cstart[NCELL];
  __shared__ int      ccur[NCELL];
  __shared__ unsigned abx[NCELL], aby[NCELL], abz[NCELL];
  __shared__ unsigned aBx[NCELL], aBy[NCELL], aBz[NCELL];
  __shared__ float    s_wv[2][8];
  __shared__ int      s_wi[2][8];

  const int b = blockIdx.x;
  const float* base = xyz + (size_t)b * NPTS * 3;
  float4* sp = ws + (size_t)b * NPTS;
  const int t = threadIdx.x;
  const int lane = t & 63, w = t >> 6;     // 8 waves

  // ---- prologue: bin + AABB + prefix + scatter ----
  cnt[t] = 0;
  abx[t] = 0xFFFFFFFFu; aby[t] = 0xFFFFFFFFu; abz[t] = 0xFFFFFFFFu;
  aBx[t] = 0u;          aBy[t] = 0u;          aBz[t] = 0u;
  __syncthreads();

  for (int k = 0; k < 32; ++k) {
    int idx = (k << 9) + t;
    const float* p = base + (size_t)idx * 3;
    float x = p[0], y = p[1], z = p[2];
    int ix = (int)(x * 8.0f); ix = ix < 0 ? 0 : (ix > 7 ? 7 : ix);
    int iy = (int)(y * 8.0f); iy = iy < 0 ? 0 : (iy > 7 ? 7 : iy);
    int iz = (int)(z * 8.0f); iz = iz < 0 ? 0 : (iz > 7 ? 7 : iz);
    int ci = ix | (iy << 3) | (iz << 6);
    atomicAdd(&cnt[ci], 1);
    atomicMin(&abx[ci], f2o(x)); atomicMax(&aBx[ci], f2o(x));
    atomicMin(&aby[ci], f2o(y)); atomicMax(&aBy[ci], f2o(y));
    atomicMin(&abz[ci], f2o(z)); atomicMax(&aBz[ci], f2o(z));
  }
  __syncthreads();

  if (w == 0) {                            // wave 0: prefix sum of 512 counts
    int loc[8]; int s = 0;
#pragma unroll
    for (int i = 0; i < 8; ++i) { loc[i] = s; s += cnt[lane * 8 + i]; }
    int run = s;
#pragma unroll
    for (int off = 1; off < 64; off <<= 1) {
      int o = __shfl_up(run, off);
      if (lane >= off) run += o;
    }
    int excl = run - s;
#pragma unroll
    for (int i = 0; i < 8; ++i) cstart[lane * 8 + i] = excl + loc[i];
  }
  __syncthreads();
  ccur[t] = cstart[t];
  __syncthreads();

  for (int k = 0; k < 32; ++k) {
    int idx = (k << 9) + t;
    const float* p = base + (size_t)idx * 3;
    float x = p[0], y = p[1], z = p[2];
    int ix = (int)(x * 8.0f); ix = ix < 0 ? 0 : (ix > 7 ? 7 : ix);
    int iy = (int)(y * 8.0f); iy = iy < 0 ? 0 : (iy > 7 ? 7 : iy);
    int iz = (int)(z * 8.0f); iz = iz < 0 ? 0 : (iz > 7 ? 7 : iz);
    int ci = ix | (iy << 3) | (iz << 6);
    int pos = atomicAdd(&ccur[ci], 1);
    sp[pos] = make_float4(x, y, z, __int_as_float(idx));
    dd[pos] = 1e10f;
  }
  __threadfence_block();
  __syncthreads();

  const int mystart = cstart[t], mycnt = cnt[t];
  float bxlo, bylo, bzlo, bxhi, byhi, bzhi;
  if (mycnt > 0) {
    bxlo = o2f(abx[t]); bxhi = o2f(aBx[t]);
    bylo = o2f(aby[t]); byhi = o2f(aBy[t]);
    bzlo = o2f(abz[t]); bzhi = o2f(aBz[t]);
  } else {
    bxlo = bxhi = bylo = byhi = bzlo = bzhi = 1e3f;   // far away: always skip
  }
  float cmax = (mycnt > 0) ? 1e10f : -1.0f;           // force full scan @it=0
  int   cargi = 0;

  const float4* cp = sp + mystart;
  float* dp = dd + mystart;

  float cx = base[0], cy = base[1], cz = base[2];

  for (int it = 0; it < NPOINT; ++it) {
    if (t == 0) {                       // record centroid (pre-update far)
      int o = (b * NPOINT + it) * 3;
      out_newxyz[o + 0] = cx;
      out_newxyz[o + 1] = cy;
      out_newxyz[o + 2] = cz;
    }

    // conservative lower bound of dist^2(centroid, cell AABB)
    float qx = fminf(fmaxf(cx, bxlo), bxhi);
    float qy = fminf(fmaxf(cy, bylo), byhi);
    float qz = fminf(fmaxf(cz, bzlo), bzhi);
    float ex = cx - qx, ey = cy - qy, ez = cz - qz;
    float lb2 = (ex * ex + ey * ey) + ez * ez;

    if (!(lb2 > cmax + 1e-5f)) {        // rescan cell (min() may change dd)
      float m = -1.0f; int mi = 0;
#define UPD(Q, E, PI) { \
      float dx = (Q).x - cx, dy = (Q).y - cy, dz = (Q).z - cz; \
      float d2 = (dx * dx + dy * dy) + dz * dz; \
      float nd = fminf((E), d2); \
      dp[PI] = nd; \
      int qi = __float_as_int((Q).w); \
      bool tk = (nd > m) || (nd == m && qi < mi); \
      m = tk ? nd : m; \
      mi = tk ? qi : mi; }
      int p = 0;
      for (; p + 4 <= mycnt; p += 4) {  // 4 loads in flight
        float4 q0 = cp[p], q1 = cp[p + 1], q2 = cp[p + 2], q3 = cp[p + 3];
        float  e0 = dp[p], e1 = dp[p + 1], e2 = dp[p + 2], e3 = dp[p + 3];
        UPD(q0, e0, p); UPD(q1, e1, p + 1); UPD(q2, e2, p + 2); UPD(q3, e3, p + 3);
      }
      for (; p < mycnt; ++p) {
        float4 q = cp[p]; float e = dp[p];
        UPD(q, e, p);
      }
#undef UPD
      cmax = m; cargi = mi;
    }

    float bv = cmax; int bi = cargi;

    // wave argmax via DPP (VALU pipe); result valid in lane 63
    amax_dpp<0x121, 0xf>(bv, bi);       // row_ror:1
    amax_dpp<0x122, 0xf>(bv, bi);       // row_ror:2
    amax_dpp<0x124, 0xf>(bv, bi);       // row_ror:4
    amax_dpp<0x128, 0xf>(bv, bi);       // row_ror:8  -> row maxima
    amax_dpp<0x142, 0xa>(bv, bi);       // row_bcast15 -> rows 1,3
    amax_dpp<0x143, 0xc>(bv, bi);       // row_bcast31 -> lane63 has full wave

    const int par = it & 1;
    if (lane == 63) { s_wv[par][w] = bv; s_wi[par][w] = bi; }
    __syncthreads();

    float gv = s_wv[par][lane & 7];     // same-address broadcast: no conflicts
    int   gi = s_wi[par][lane & 7];
    amax_dpp<0x121, 0xf>(gv, gi);       // combine 8 wave results (period-8)
    amax_dpp<0x122, 0xf>(gv, gi);
    amax_dpp<0x124, 0xf>(gv, gi);

    int far = __builtin_amdgcn_readfirstlane(gi);
    cx = base[far * 3 + 0];             // uniform centroid load (L2-resident)
    cy = base[far * 3 + 1];
    cz = base[far * 3 + 2];
  }
}

// ---------------------------------------------------------------------------
// Fallback single-block FPS (R7 version, verified) when ws is too small.
// ---------------------------------------------------------------------------
__global__ void __launch_bounds__(FPS_T)
fps_single(const float* __restrict__ xyz, float* __restrict__ out_newxyz)
{
  __shared__ float px[FPS_T * FPS_PAD];
  __shared__ float py[FPS_T * FPS_PAD];
  __shared__ float s_wv[2][8];
  __shared__ int   s_wi[2][8];

  const int b = blockIdx.x;
  const float* base = xyz + (size_t)b * NPTS * 3;
  const int t = threadIdx.x;
  const int lane = t & 63, w = t >> 6;
  const int t34 = t * FPS_PAD;

#define INITP(j) v2f pz##j, dd##j; { \
    const float* p0 = base + (size_t)(((2*(j)) << 9) + t) * 3; \
    const float* p1 = base + (size_t)(((2*(j)+1) << 9) + t) * 3; \
    px[t34 + 2*(j)]     = p0[0];  px[t34 + 2*(j) + 1] = p1[0]; \
    py[t34 + 2*(j)]     = p0[1];  py[t34 + 2*(j) + 1] = p1[1]; \
    pz##j.x = p0[2];  pz##j.y = p1[2]; \
    dd##j.x = 1e10f;  dd##j.y = 1e10f; }
  RPT16(INITP)
#undef INITP

  float cx = base[0], cy = base[1], cz = base[2];

  for (int it = 0; it < NPOINT; ++it) {
#define PINJ(j) asm volatile("" : "+v"(pz##j), "+v"(dd##j));
    RPT16(PINJ)
#undef PINJ
    if (t == 0) {
      int o = (b * NPOINT + it) * 3;
      out_newxyz[o + 0] = cx;
      out_newxyz[o + 1] = cy;
      out_newxyz[o + 2] = cz;
    }
    v2f cx2, cy2, cz2;
    cx2.x = cx; cx2.y = cx; cy2.x = cy; cy2.y = cy; cz2.x = cz; cz2.y = cz;
    float bv = -1.0f; int bl = 0;
#define STEP2(j) { \
    v2f xx = *reinterpret_cast<const v2f*>(&px[t34 + 2*(j)]); \
    v2f yy = *reinterpret_cast<const v2f*>(&py[t34 + 2*(j)]); \
    v2f dx = xx - cx2; \
    v2f dy = yy - cy2; \
    v2f dz = pz##j - cz2; \
    v2f d2 = (dx * dx + dy * dy) + dz * dz; \
    v2f nd; \
    nd.x = fminf(dd##j.x, d2.x); \
    nd.y = fminf(dd##j.y, d2.y); \
    dd##j = nd; \
    float m = fmaxf(nd.x, nd.y); \
    int kw = (nd.x >= nd.y) ? (2*(j)) : (2*(j)+1); \
    bool tk = m > bv; \
    bv = tk ? m : bv; \
    bl = tk ? kw : bl; }
    RPT16(STEP2)
#undef STEP2
    int bi = (bl << 9) + t;

    amax_dpp<0x121, 0xf>(bv, bi);
    amax_dpp<0x122, 0xf>(bv, bi);
    amax_dpp<0x124, 0xf>(bv, bi);
    amax_dpp<0x128, 0xf>(bv, bi);
    amax_dpp<0x142, 0xa>(bv, bi);
    amax_dpp<0x143, 0xc>(bv, bi);

    const int par = it & 1;
    if (lane == 63) { s_wv[par][w] = bv; s_wi[par][w] = bi; }
    __syncthreads();

    float gv = s_wv[par][lane & 7];
    int   gi = s_wi[par][lane & 7];
    amax_dpp<0x121, 0xf>(gv, gi);
    amax_dpp<0x122, 0xf>(gv, gi);
    amax_dpp<0x124, 0xf>(gv, gi);

    int far = __builtin_amdgcn_readfirstlane(gi);
    cx = base[far * 3 + 0];
    cy = base[far * 3 + 1];
    cz = base[far * 3 + 2];
  }
}

// ---------------------------------------------------------------------------
// features (B,64,N) -> featsT (B,N,64) so per-neighbor gathers are contiguous.
// ---------------------------------------------------------------------------
__global__ __launch_bounds__(256) void transpose_kernel(
    const float* __restrict__ f, float* __restrict__ ft)
{
  __shared__ float tile[64][65];
  int b  = blockIdx.x >> 8;
  int n0 = (blockIdx.x & 255) << 6;
  for (int v = threadIdx.x; v < 64 * 64; v += 256) {
    int c = v >> 6, j = v & 63;
    tile[c][j] = f[((size_t)(b * 64 + c)) * NPTS + n0 + j];
  }
  __syncthreads();
  for (int v = threadIdx.x; v < 64 * 64; v += 256) {
    int j = v >> 6, c = v & 63;
    ft[((size_t)(b * NPTS + n0 + j)) * 64 + c] = tile[c][j];
  }
}

// ---------------------------------------------------------------------------
// Fused ball-query + gather + 3-layer MLP + max-pool. (unchanged this round)
// Block = 1024 threads, 8 centers/block, grid = 512.
// ---------------------------------------------------------------------------
__global__ __launch_bounds__(1024) void mlp_kernel(
    const float* __restrict__ xyz,
    const float* __restrict__ feats,      // (B,64,N)
    const float* __restrict__ featsT,     // (B,N,64) or null
    const float* __restrict__ nx,         // new_xyz = d_out base (B,1024,3)
    const float* __restrict__ W1, const float* __restrict__ s1, const float* __restrict__ b1,
    const float* __restrict__ W2, const float* __restrict__ s2, const float* __restrict__ b2,
    const float* __restrict__ W3, const float* __restrict__ s3, const float* __restrict__ b3,
    float* __restrict__ outF)             // d_out + 12288, (B,128,1024)
{
  __shared__ float W1t[CIN * 64];     // [i][o]
  __shared__ float W2t[64 * 64];      // [i][o]
  __shared__ float sb[512];           // s1 b1 s2 b2 s3 b3
  __shared__ float xs[CIN * 34];      // [c][k], pad 34 (2-way = free)
  __shared__ float h1[64 * 34];
  __shared__ float h2[64 * 34];
  __shared__ int   hm[128];
  __shared__ int   lid8[8][NSAMPLE];

  const int tid = threadIdx.x;
  const int lane = tid & 63, w = tid >> 6;

  for (int v = tid; v < CIN * 64; v += 1024) {
    int o = v / CIN, i = v - o * CIN;
    W1t[i * 64 + o] = W1[v];
  }
  for (int v = tid; v < 64 * 64; v += 1024) {
    int o = v >> 6, i = v & 63;
    W2t[i * 64 + o] = W2[v];
  }
  if (tid < 64)       sb[tid]       = s1[tid];
  else if (tid < 128) sb[tid]       = b1[tid - 64];
  else if (tid < 192) sb[tid]       = s2[tid - 128];
  else if (tid < 256) sb[tid]       = b2[tid - 192];
  else if (tid < 384) sb[tid]       = s3[tid - 256];
  else if (tid < 512) sb[tid]       = b3[tid - 384];

  // ---- Phase 0: ball query, one wave per center ----
  if (w < 8) {
    int g = (blockIdx.x << 3) + w;
    int b = g >> 10;
    const float* base = xyz + (size_t)b * NPTS * 3;
    float cx = nx[g * 3 + 0], cy = nx[g * 3 + 1], cz = nx[g * 3 + 2];
    int cnt = 0, fidx = -1;
    for (int c0 = 0; c0 < NPTS && cnt < NSAMPLE; c0 += 64) {
      int i = c0 + lane;
      float dx = __fsub_rn(base[i * 3 + 0], cx);
      float dy = __fsub_rn(base[i * 3 + 1], cy);
      float dz = __fsub_rn(base[i * 3 + 2], cz);
      float d2 = __fadd_rn(__fadd_rn(__fmul_rn(dx, dx), __fmul_rn(dy, dy)),
                           __fmul_rn(dz, dz));
      bool pred = d2 < R2f;
      unsigned long long mk = __ballot(pred);
      if (pred) {
        int rank = cnt + __popcll(mk & ((1ull << lane) - 1ull));
        if (rank < NSAMPLE) lid8[w][rank] = i;
        if (rank == 0) fidx = i;
      }
      cnt += __popcll(mk);
    }
#pragma unroll
    for (int off = 32; off >= 1; off >>= 1) {
      int o = __shfl_xor(fidx, off);
      fidx = o > fidx ? o : fidx;
    }
    if (lane >= cnt && lane < NSAMPLE) lid8[w][lane] = fidx;
  }
  __syncthreads();

  // ---- per-center MLP ----
  for (int ci = 0; ci < 8; ++ci) {
    int g = (blockIdx.x << 3) + ci;
    int b = g >> 10, m = g & 1023;

    // gather xs[c][k]  (+ init hm)
    {
      int k = tid >> 5, c0 = tid & 31;
      int id = lid8[ci][k];
      for (int c = c0; c < CIN; c += 32) {
        float val;
        if (c < 3)
          val = __fsub_rn(xyz[((size_t)b * NPTS + id) * 3 + c], nx[g * 3 + c]);
        else if (featsT)
          val = featsT[((size_t)b * NPTS + id) * 64 + (c - 3)];
        else
          val = feats[((size_t)(b * 64 + (c - 3))) * NPTS + id];
        xs[c * 34 + k] = val;
      }
      if (tid < 128) hm[tid] = 0;
    }
    __syncthreads();

    // L1: 67 -> 64
    {
      int oc = tid & 63, k0 = (tid >> 6) << 1;
      float a0 = 0.f, a1 = 0.f;
#pragma unroll 4
      for (int i = 0; i < CIN; ++i) {
        float ww = W1t[i * 64 + oc];
        a0 = fmaf(ww, xs[i * 34 + k0], a0);
        a1 = fmaf(ww, xs[i * 34 + k0 + 1], a1);
      }
      float s = sb[oc], bb = sb[64 + oc];
      h1[oc * 34 + k0]     = fmaxf(fmaf(a0, s, bb), 0.f);
      h1[oc * 34 + k0 + 1] = fmaxf(fmaf(a1, s, bb), 0.f);
    }
    __syncthreads();

    // L2: 64 -> 64
    {
      int oc = tid & 63, k0 = (tid >> 6) << 1;
      float a0 = 0.f, a1 = 0.f;
#pragma unroll 4
      for (int i = 0; i < 64; ++i) {
        float ww = W2t[i * 64 + oc];
        a0 = fmaf(ww, h1[i * 34 + k0], a0);
        a1 = fmaf(ww, h1[i * 34 + k0 + 1], a1);
      }
      float s = sb[128 + oc], bb = sb[192 + oc];
      h2[oc * 34 + k0]     = fmaxf(fmaf(a0, s, bb), 0.f);
      h2[oc * 34 + k0 + 1] = fmaxf(fmaf(a1, s, bb), 0.f);
    }
    __syncthreads();

    // L3: 64 -> 128, fused max over k
    {
      int oc = tid & 127, k0 = (tid >> 7) << 2;
      const float4* W3v = reinterpret_cast<const float4*>(W3);
      float a0 = 0.f, a1 = 0.f, a2 = 0.f, a3 = 0.f;
#pragma unroll 4
      for (int i4 = 0; i4 < 16; ++i4) {
        float4 wv = W3v[oc * 16 + i4];
        const float* hr = &h2[(i4 * 4) * 34 + k0];
        a0 = fmaf(wv.x, hr[0], a0); a1 = fmaf(wv.x, hr[1], a1);
        a2 = fmaf(wv.x, hr[2], a2); a3 = fmaf(wv.x, hr[3], a3);
        hr += 34;
        a0 = fmaf(wv.y, hr[0], a0); a1 = fmaf(wv.y, hr[1], a1);
        a2 = fmaf(wv.y, hr[2], a2); a3 = fmaf(wv.y, hr[3], a3);
        hr += 34;
        a0 = fmaf(wv.z, hr[0], a0); a1 = fmaf(wv.z, hr[1], a1);
        a2 = fmaf(wv.z, hr[2], a2); a3 = fmaf(wv.z, hr[3], a3);
        hr += 34;
        a0 = fmaf(wv.w, hr[0], a0); a1 = fmaf(wv.w, hr[1], a1);
        a2 = fmaf(wv.w, hr[2], a2); a3 = fmaf(wv.w, hr[3], a3);
      }
      float s = sb[256 + oc], bb = sb[384 + oc];
      float v0 = fmaxf(fmaf(a0, s, bb), 0.f);
      float v1 = fmaxf(fmaf(a1, s, bb), 0.f);
      float v2 = fmaxf(fmaf(a2, s, bb), 0.f);
      float v3 = fmaxf(fmaf(a3, s, bb), 0.f);
      float mv = fmaxf(fmaxf(v0, v1), fmaxf(v2, v3));
      atomicMax(&hm[oc], __float_as_int(mv));   // values >= 0: int order == float order
    }
    __syncthreads();

    if (tid < 128)
      outF[(((size_t)b * 128 + tid) << 10) + m] = __int_as_float(hm[tid]);
    __syncthreads();
  }
}

// ---------------------------------------------------------------------------
extern "C" void kernel_launch(void* const* d_in, const int* in_sizes, int n_in,
                              void* d_out, int out_size, void* d_ws, size_t ws_size,
                              hipStream_t stream)
{
  if (n_in < 11) return;
  const float* xyz   = (const float*)d_in[0];
  const float* feats = (const float*)d_in[1];
  const float* W1 = (const float*)d_in[2];
  const float* s1 = (const float*)d_in[3];
  const float* b1 = (const float*)d_in[4];
  const float* W2 = (const float*)d_in[5];
  const float* s2 = (const float*)d_in[6];
  const float* b2 = (const float*)d_in[7];
  const float* W3 = (const float*)d_in[8];
  const float* s3 = (const float*)d_in[9];
  const float* b3 = (const float*)d_in[10];
  float* out = (float*)d_out;

  // ws layout: [0, gridBytes) sorted-point scratch for fps_grid; featsT after.
  size_t gridBytes = (size_t)BATCH * NPTS * sizeof(float4);   // 1 MB
  size_t needT = (size_t)BATCH * NPTS * 64 * sizeof(float);
  float* featsT = nullptr;
  if (ws_size >= gridBytes + needT)
    featsT = (float*)((char*)d_ws + gridBytes);

  if (ws_size >= gridBytes)
    fps_grid<<<BATCH, FPS_T, 0, stream>>>(xyz, out, (float4*)d_ws);
  else
    fps_single<<<BATCH, FPS_T, 0, stream>>>(xyz, out);

  if (featsT) transpose_kernel<<<BATCH * 256, 256, 0, stream>>>(feats, featsT);
  mlp_kernel<<<512, 1024, 0, stream>>>(xyz, feats, featsT, out,
                                       W1, s1, b1, W2, s2, b2, W3, s3, b3,
                                       out + BATCH * NPOINT * 3);
}

// Round 10
// 3214.743 us; speedup vs baseline: 1.7978x; 1.7978x over previous
//
#include <hip/hip_runtime.h>
#include <cstdint>
#include <cstddef>

// Exactness: prevent mul+add fusion everywhere (XLA ref uses unfused
// (dx*dx+dy*dy)+dz*dz). Explicit fmaf() calls in mlp_kernel are unaffected.
#pragma clang fp contract(off)

#define BATCH   4
#define NPTS    16384
#define NPOINT  1024
#define NSAMPLE 32
#define CIN     67          // 3 + 64 feature channels
#define R2f     0.04f       // (float)(0.2*0.2)

#define FPS_T   512         // 8 waves, one block per batch
#define NCELL   512         // 8x8x8 grid
#define FPS_PAD 34          // (fallback kernel)

#define RPT16(M) M(0)M(1)M(2)M(3)M(4)M(5)M(6)M(7)M(8)M(9)M(10)M(11)M(12)M(13)M(14)M(15)

typedef float v2f __attribute__((ext_vector_type(2)));

// ---------------------------------------------------------------------------
// DPP-based argmax combine: max value, tie -> lowest index. VALU-pipe only.
// ---------------------------------------------------------------------------
template <int CTRL, int RMASK>
__device__ __forceinline__ void amax_dpp(float& v, int& i) {
  int nv = __builtin_amdgcn_update_dpp(__float_as_int(v), __float_as_int(v),
                                       CTRL, RMASK, 0xf, false);
  int ni = __builtin_amdgcn_update_dpp(i, i, CTRL, RMASK, 0xf, false);
  float fv = __int_as_float(nv);
  bool tk = (fv > v) || (fv == v && ni < i);
  v = tk ? fv : v;
  i = tk ? ni : i;
}

// float <-> order-preserving uint (for LDS atomic AABB min/max)
__device__ __forceinline__ unsigned f2o(float f) {
  unsigned u = __float_as_uint(f);
  return u ^ ((unsigned)((int)u >> 31) | 0x80000000u);
}
__device__ __forceinline__ float o2f(unsigned k) {
  unsigned u = (k & 0x80000000u) ? (k ^ 0x80000000u) : ~k;
  return __uint_as_float(u);
}

// ---------------------------------------------------------------------------
// Grid-pruned FPS, wave-cooperative rescan. R9 post-mortem: pruning worked
// (passed, VALU issue -4x) but thread-per-cell rescan SERIALIZED each cell
// behind one lane's dependent L2-load chain while 480+ threads idled at the
// barrier (VALUBusy 0.28% = 18% of the 4-CU ceiling; 5.5us/iter). Fix:
//  Phase A: thread t decides skip/rescan for cell t via lb2 vs cmaxv[t]
//           (cached cell max, now in LDS); pushes rescan cells to a worklist.
//  Phase B: 8 waves POP cells dynamically; 64 lanes scan a cell's points in
//           PARALLEL (1 L2 round-trip, stride-1 dd -> conflict-free), wave
//           DPP argmax (tie -> lowest ORIGINAL idx), lane63 refreshes
//           cmaxv/cargv.
//  Phase C: thread t reads its cell's candidate; block DPP argmax (as ever).
// Skip bound unchanged (HW-verified exact in R9): lb2 > cmax + 1e-5 proves
// fminf is a no-op for every point in the cell; dd evolution bit-identical.
// 3 barriers/iter. LDS ~90 KB.
// ---------------------------------------------------------------------------
__global__ void __launch_bounds__(FPS_T)
fps_grid(const float* __restrict__ xyz, float* __restrict__ out_newxyz,
         float4* __restrict__ ws)          // [BATCH][NPTS] sorted points
{
  __shared__ float    dd[NPTS];            // 64 KB, by sorted pos
  __shared__ int      cnt[NCELL];
  __shared__ int      cstart[NCELL];
  __shared__ int      ccur[NCELL];
  __shared__ unsigned abx[NCELL], aby[NCELL], abz[NCELL];
  __shared__ unsigned aBx[NCELL], aBy[NCELL], aBz[NCELL];
  __shared__ float    cmaxv[NCELL];        // cached per-cell max(dd)
  __shared__ int      cargv[NCELL];        // cached per-cell argmax (orig idx)
  __shared__ int      wl[NCELL];           // rescan worklist
  __shared__ int      nact, cursor;
  __shared__ float    s_wv[2][8];
  __shared__ int      s_wi[2][8];

  const int b = blockIdx.x;
  const float* base = xyz + (size_t)b * NPTS * 3;
  float4* sp = ws + (size_t)b * NPTS;
  const int t = threadIdx.x;
  const int lane = t & 63, w = t >> 6;     // 8 waves

  // ---- prologue: bin + AABB + prefix + scatter (verified R9) ----
  cnt[t] = 0;
  abx[t] = 0xFFFFFFFFu; aby[t] = 0xFFFFFFFFu; abz[t] = 0xFFFFFFFFu;
  aBx[t] = 0u;          aBy[t] = 0u;          aBz[t] = 0u;
  __syncthreads();

  for (int k = 0; k < 32; ++k) {
    int idx = (k << 9) + t;
    const float* p = base + (size_t)idx * 3;
    float x = p[0], y = p[1], z = p[2];
    int ix = (int)(x * 8.0f); ix = ix < 0 ? 0 : (ix > 7 ? 7 : ix);
    int iy = (int)(y * 8.0f); iy = iy < 0 ? 0 : (iy > 7 ? 7 : iy);
    int iz = (int)(z * 8.0f); iz = iz < 0 ? 0 : (iz > 7 ? 7 : iz);
    int ci = ix | (iy << 3) | (iz << 6);
    atomicAdd(&cnt[ci], 1);
    atomicMin(&abx[ci], f2o(x)); atomicMax(&aBx[ci], f2o(x));
    atomicMin(&aby[ci], f2o(y)); atomicMax(&aBy[ci], f2o(y));
    atomicMin(&abz[ci], f2o(z)); atomicMax(&aBz[ci], f2o(z));
  }
  __syncthreads();

  if (w == 0) {                            // wave 0: prefix sum of 512 counts
    int loc[8]; int s = 0;
#pragma unroll
    for (int i = 0; i < 8; ++i) { loc[i] = s; s += cnt[lane * 8 + i]; }
    int run = s;
#pragma unroll
    for (int off = 1; off < 64; off <<= 1) {
      int o = __shfl_up(run, off);
      if (lane >= off) run += o;
    }
    int excl = run - s;
#pragma unroll
    for (int i = 0; i < 8; ++i) cstart[lane * 8 + i] = excl + loc[i];
  }
  __syncthreads();
  ccur[t] = cstart[t];
  __syncthreads();

  for (int k = 0; k < 32; ++k) {
    int idx = (k << 9) + t;
    const float* p = base + (size_t)idx * 3;
    float x = p[0], y = p[1], z = p[2];
    int ix = (int)(x * 8.0f); ix = ix < 0 ? 0 : (ix > 7 ? 7 : ix);
    int iy = (int)(y * 8.0f); iy = iy < 0 ? 0 : (iy > 7 ? 7 : iy);
    int iz = (int)(z * 8.0f); iz = iz < 0 ? 0 : (iz > 7 ? 7 : iz);
    int ci = ix | (iy << 3) | (iz << 6);
    int pos = atomicAdd(&ccur[ci], 1);
    sp[pos] = make_float4(x, y, z, __int_as_float(idx));
    dd[pos] = 1e10f;
  }
  cmaxv[t] = (cnt[t] > 0) ? 1e10f : -1.0f;  // force rescan of all @ it=0
  cargv[t] = 0;
  if (t == 0) { nact = 0; cursor = 0; }
  __threadfence_block();
  __syncthreads();

  // per-thread cell constants (cell t)
  const int mycnt = cnt[t];
  float bxlo, bylo, bzlo, bxhi, byhi, bzhi;
  if (mycnt > 0) {
    bxlo = o2f(abx[t]); bxhi = o2f(aBx[t]);
    bylo = o2f(aby[t]); byhi = o2f(aBy[t]);
    bzlo = o2f(abz[t]); bzhi = o2f(aBz[t]);
  } else {
    bxlo = bxhi = bylo = byhi = bzlo = bzhi = 1e3f;   // far away: never rescan
  }

  float cx = base[0], cy = base[1], cz = base[2];

  for (int it = 0; it < NPOINT; ++it) {
    if (t == 0) {                       // record centroid (pre-update far)
      int o = (b * NPOINT + it) * 3;
      out_newxyz[o + 0] = cx;
      out_newxyz[o + 1] = cy;
      out_newxyz[o + 2] = cz;
    }

    // ---- phase A: skip test for own cell ----
    float qx = fminf(fmaxf(cx, bxlo), bxhi);
    float qy = fminf(fmaxf(cy, bylo), byhi);
    float qz = fminf(fmaxf(cz, bzlo), bzhi);
    float ex = cx - qx, ey = cy - qy, ez = cz - qz;
    float lb2 = (ex * ex + ey * ey) + ez * ez;
    if (mycnt > 0 && !(lb2 > cmaxv[t] + 1e-5f)) {
      int pos = atomicAdd(&nact, 1);
      wl[pos] = t;
    }
    __syncthreads();                    // B1: worklist complete
    const int nactL = nact;

    // ---- phase B: waves cooperatively rescan worklist cells ----
    for (;;) {
      int myidx = 0;
      if (lane == 0) myidx = atomicAdd(&cursor, 1);
      myidx = __builtin_amdgcn_readfirstlane(myidx);
      if (myidx >= nactL) break;
      int ci = wl[myidx];
      int st = cstart[ci], cn = cnt[ci];
      float m = -1.0f; int mi = 0;
      for (int p = lane; p < cn; p += 64) {
        float4 q = sp[st + p];          // L2-resident, lanes parallel
        float  e = dd[st + p];          // stride-1: conflict-free
        float dx = q.x - cx, dy = q.y - cy, dz = q.z - cz;
        float d2 = (dx * dx + dy * dy) + dz * dz;
        float nd = fminf(e, d2);
        dd[st + p] = nd;
        int qi = __float_as_int(q.w);
        bool tk = (nd > m) || (nd == m && qi < mi);
        m = tk ? nd : m;
        mi = tk ? qi : mi;
      }
      amax_dpp<0x121, 0xf>(m, mi);      // wave argmax, valid in lane 63
      amax_dpp<0x122, 0xf>(m, mi);
      amax_dpp<0x124, 0xf>(m, mi);
      amax_dpp<0x128, 0xf>(m, mi);
      amax_dpp<0x142, 0xa>(m, mi);
      amax_dpp<0x143, 0xc>(m, mi);
      if (lane == 63) { cmaxv[ci] = m; cargv[ci] = mi; }
    }
    __syncthreads();                    // B2: cmaxv/cargv refreshed

    // ---- phase C: block argmax over per-cell candidates ----
    float bv = cmaxv[t]; int bi = cargv[t];
    amax_dpp<0x121, 0xf>(bv, bi);
    amax_dpp<0x122, 0xf>(bv, bi);
    amax_dpp<0x124, 0xf>(bv, bi);
    amax_dpp<0x128, 0xf>(bv, bi);
    amax_dpp<0x142, 0xa>(bv, bi);
    amax_dpp<0x143, 0xc>(bv, bi);

    const int par = it & 1;
    if (lane == 63) { s_wv[par][w] = bv; s_wi[par][w] = bi; }
    if (t == 0) { nact = 0; cursor = 0; }   // reset for next iter (pre-B3)
    __syncthreads();                    // B3

    float gv = s_wv[par][lane & 7];     // same-address broadcast: no conflicts
    int   gi = s_wi[par][lane & 7];
    amax_dpp<0x121, 0xf>(gv, gi);       // combine 8 wave results (period-8)
    amax_dpp<0x122, 0xf>(gv, gi);
    amax_dpp<0x124, 0xf>(gv, gi);

    int far = __builtin_amdgcn_readfirstlane(gi);
    cx = base[far * 3 + 0];             // uniform centroid load (L2-resident)
    cy = base[far * 3 + 1];
    cz = base[far * 3 + 2];
  }
}

// ---------------------------------------------------------------------------
// Fallback single-block FPS (R7 version, verified) when ws is too small.
// ---------------------------------------------------------------------------
__global__ void __launch_bounds__(FPS_T)
fps_single(const float* __restrict__ xyz, float* __restrict__ out_newxyz)
{
  __shared__ float px[FPS_T * FPS_PAD];
  __shared__ float py[FPS_T * FPS_PAD];
  __shared__ float s_wv[2][8];
  __shared__ int   s_wi[2][8];

  const int b = blockIdx.x;
  const float* base = xyz + (size_t)b * NPTS * 3;
  const int t = threadIdx.x;
  const int lane = t & 63, w = t >> 6;
  const int t34 = t * FPS_PAD;

#define INITP(j) v2f pz##j, dd##j; { \
    const float* p0 = base + (size_t)(((2*(j)) << 9) + t) * 3; \
    const float* p1 = base + (size_t)(((2*(j)+1) << 9) + t) * 3; \
    px[t34 + 2*(j)]     = p0[0];  px[t34 + 2*(j) + 1] = p1[0]; \
    py[t34 + 2*(j)]     = p0[1];  py[t34 + 2*(j) + 1] = p1[1]; \
    pz##j.x = p0[2];  pz##j.y = p1[2]; \
    dd##j.x = 1e10f;  dd##j.y = 1e10f; }
  RPT16(INITP)
#undef INITP

  float cx = base[0], cy = base[1], cz = base[2];

  for (int it = 0; it < NPOINT; ++it) {
#define PINJ(j) asm volatile("" : "+v"(pz##j), "+v"(dd##j));
    RPT16(PINJ)
#undef PINJ
    if (t == 0) {
      int o = (b * NPOINT + it) * 3;
      out_newxyz[o + 0] = cx;
      out_newxyz[o + 1] = cy;
      out_newxyz[o + 2] = cz;
    }
    v2f cx2, cy2, cz2;
    cx2.x = cx; cx2.y = cx; cy2.x = cy; cy2.y = cy; cz2.x = cz; cz2.y = cz;
    float bv = -1.0f; int bl = 0;
#define STEP2(j) { \
    v2f xx = *reinterpret_cast<const v2f*>(&px[t34 + 2*(j)]); \
    v2f yy = *reinterpret_cast<const v2f*>(&py[t34 + 2*(j)]); \
    v2f dx = xx - cx2; \
    v2f dy = yy - cy2; \
    v2f dz = pz##j - cz2; \
    v2f d2 = (dx * dx + dy * dy) + dz * dz; \
    v2f nd; \
    nd.x = fminf(dd##j.x, d2.x); \
    nd.y = fminf(dd##j.y, d2.y); \
    dd##j = nd; \
    float m = fmaxf(nd.x, nd.y); \
    int kw = (nd.x >= nd.y) ? (2*(j)) : (2*(j)+1); \
    bool tk = m > bv; \
    bv = tk ? m : bv; \
    bl = tk ? kw : bl; }
    RPT16(STEP2)
#undef STEP2
    int bi = (bl << 9) + t;

    amax_dpp<0x121, 0xf>(bv, bi);
    amax_dpp<0x122, 0xf>(bv, bi);
    amax_dpp<0x124, 0xf>(bv, bi);
    amax_dpp<0x128, 0xf>(bv, bi);
    amax_dpp<0x142, 0xa>(bv, bi);
    amax_dpp<0x143, 0xc>(bv, bi);

    const int par = it & 1;
    if (lane == 63) { s_wv[par][w] = bv; s_wi[par][w] = bi; }
    __syncthreads();

    float gv = s_wv[par][lane & 7];
    int   gi = s_wi[par][lane & 7];
    amax_dpp<0x121, 0xf>(gv, gi);
    amax_dpp<0x122, 0xf>(gv, gi);
    amax_dpp<0x124, 0xf>(gv, gi);

    int far = __builtin_amdgcn_readfirstlane(gi);
    cx = base[far * 3 + 0];
    cy = base[far * 3 + 1];
    cz = base[far * 3 + 2];
  }
}

// ---------------------------------------------------------------------------
// features (B,64,N) -> featsT (B,N,64) so per-neighbor gathers are contiguous.
// ---------------------------------------------------------------------------
__global__ __launch_bounds__(256) void transpose_kernel(
    const float* __restrict__ f, float* __restrict__ ft)
{
  __shared__ float tile[64][65];
  int b  = blockIdx.x >> 8;
  int n0 = (blockIdx.x & 255) << 6;
  for (int v = threadIdx.x; v < 64 * 64; v += 256) {
    int c = v >> 6, j = v & 63;
    tile[c][j] = f[((size_t)(b * 64 + c)) * NPTS + n0 + j];
  }
  __syncthreads();
  for (int v = threadIdx.x; v < 64 * 64; v += 256) {
    int j = v >> 6, c = v & 63;
    ft[((size_t)(b * NPTS + n0 + j)) * 64 + c] = tile[c][j];
  }
}

// ---------------------------------------------------------------------------
// Fused ball-query + gather + 3-layer MLP + max-pool. (unchanged this round)
// Block = 1024 threads, 8 centers/block, grid = 512.
// ---------------------------------------------------------------------------
__global__ __launch_bounds__(1024) void mlp_kernel(
    const float* __restrict__ xyz,
    const float* __restrict__ feats,      // (B,64,N)
    const float* __restrict__ featsT,     // (B,N,64) or null
    const float* __restrict__ nx,         // new_xyz = d_out base (B,1024,3)
    const float* __restrict__ W1, const float* __restrict__ s1, const float* __restrict__ b1,
    const float* __restrict__ W2, const float* __restrict__ s2, const float* __restrict__ b2,
    const float* __restrict__ W3, const float* __restrict__ s3, const float* __restrict__ b3,
    float* __restrict__ outF)             // d_out + 12288, (B,128,1024)
{
  __shared__ float W1t[CIN * 64];     // [i][o]
  __shared__ float W2t[64 * 64];      // [i][o]
  __shared__ float sb[512];           // s1 b1 s2 b2 s3 b3
  __shared__ float xs[CIN * 34];      // [c][k], pad 34 (2-way = free)
  __shared__ float h1[64 * 34];
  __shared__ float h2[64 * 34];
  __shared__ int   hm[128];
  __shared__ int   lid8[8][NSAMPLE];

  const int tid = threadIdx.x;
  const int lane = tid & 63, w = tid >> 6;

  for (int v = tid; v < CIN * 64; v += 1024) {
    int o = v / CIN, i = v - o * CIN;
    W1t[i * 64 + o] = W1[v];
  }
  for (int v = tid; v < 64 * 64; v += 1024) {
    int o = v >> 6, i = v & 63;
    W2t[i * 64 + o] = W2[v];
  }
  if (tid < 64)       sb[tid]       = s1[tid];
  else if (tid < 128) sb[tid]       = b1[tid - 64];
  else if (tid < 192) sb[tid]       = s2[tid - 128];
  else if (tid < 256) sb[tid]       = b2[tid - 192];
  else if (tid < 384) sb[tid]       = s3[tid - 256];
  else if (tid < 512) sb[tid]       = b3[tid - 384];

  // ---- Phase 0: ball query, one wave per center ----
  if (w < 8) {
    int g = (blockIdx.x << 3) + w;
    int b = g >> 10;
    const float* base = xyz + (size_t)b * NPTS * 3;
    float cx = nx[g * 3 + 0], cy = nx[g * 3 + 1], cz = nx[g * 3 + 2];
    int cnt = 0, fidx = -1;
    for (int c0 = 0; c0 < NPTS && cnt < NSAMPLE; c0 += 64) {
      int i = c0 + lane;
      float dx = __fsub_rn(base[i * 3 + 0], cx);
      float dy = __fsub_rn(base[i * 3 + 1], cy);
      float dz = __fsub_rn(base[i * 3 + 2], cz);
      float d2 = __fadd_rn(__fadd_rn(__fmul_rn(dx, dx), __fmul_rn(dy, dy)),
                           __fmul_rn(dz, dz));
      bool pred = d2 < R2f;
      unsigned long long mk = __ballot(pred);
      if (pred) {
        int rank = cnt + __popcll(mk & ((1ull << lane) - 1ull));
        if (rank < NSAMPLE) lid8[w][rank] = i;
        if (rank == 0) fidx = i;
      }
      cnt += __popcll(mk);
    }
#pragma unroll
    for (int off = 32; off >= 1; off >>= 1) {
      int o = __shfl_xor(fidx, off);
      fidx = o > fidx ? o : fidx;
    }
    if (lane >= cnt && lane < NSAMPLE) lid8[w][lane] = fidx;
  }
  __syncthreads();

  // ---- per-center MLP ----
  for (int ci = 0; ci < 8; ++ci) {
    int g = (blockIdx.x << 3) + ci;
    int b = g >> 10, m = g & 1023;

    // gather xs[c][k]  (+ init hm)
    {
      int k = tid >> 5, c0 = tid & 31;
      int id = lid8[ci][k];
      for (int c = c0; c < CIN; c += 32) {
        float val;
        if (c < 3)
          val = __fsub_rn(xyz[((size_t)b * NPTS + id) * 3 + c], nx[g * 3 + c]);
        else if (featsT)
          val = featsT[((size_t)b * NPTS + id) * 64 + (c - 3)];
        else
          val = feats[((size_t)(b * 64 + (c - 3))) * NPTS + id];
        xs[c * 34 + k] = val;
      }
      if (tid < 128) hm[tid] = 0;
    }
    __syncthreads();

    // L1: 67 -> 64
    {
      int oc = tid & 63, k0 = (tid >> 6) << 1;
      float a0 = 0.f, a1 = 0.f;
#pragma unroll 4
      for (int i = 0; i < CIN; ++i) {
        float ww = W1t[i * 64 + oc];
        a0 = fmaf(ww, xs[i * 34 + k0], a0);
        a1 = fmaf(ww, xs[i * 34 + k0 + 1], a1);
      }
      float s = sb[oc], bb = sb[64 + oc];
      h1[oc * 34 + k0]     = fmaxf(fmaf(a0, s, bb), 0.f);
      h1[oc * 34 + k0 + 1] = fmaxf(fmaf(a1, s, bb), 0.f);
    }
    __syncthreads();

    // L2: 64 -> 64
    {
      int oc = tid & 63, k0 = (tid >> 6) << 1;
      float a0 = 0.f, a1 = 0.f;
#pragma unroll 4
      for (int i = 0; i < 64; ++i) {
        float ww = W2t[i * 64 + oc];
        a0 = fmaf(ww, h1[i * 34 + k0], a0);
        a1 = fmaf(ww, h1[i * 34 + k0 + 1], a1);
      }
      float s = sb[128 + oc], bb = sb[192 + oc];
      h2[oc * 34 + k0]     = fmaxf(fmaf(a0, s, bb), 0.f);
      h2[oc * 34 + k0 + 1] = fmaxf(fmaf(a1, s, bb), 0.f);
    }
    __syncthreads();

    // L3: 64 -> 128, fused max over k
    {
      int oc = tid & 127, k0 = (tid >> 7) << 2;
      const float4* W3v = reinterpret_cast<const float4*>(W3);
      float a0 = 0.f, a1 = 0.f, a2 = 0.f, a3 = 0.f;
#pragma unroll 4
      for (int i4 = 0; i4 < 16; ++i4) {
        float4 wv = W3v[oc * 16 + i4];
        const float* hr = &h2[(i4 * 4) * 34 + k0];
        a0 = fmaf(wv.x, hr[0], a0); a1 = fmaf(wv.x, hr[1], a1);
        a2 = fmaf(wv.x, hr[2], a2); a3 = fmaf(wv.x, hr[3], a3);
        hr += 34;
        a0 = fmaf(wv.y, hr[0], a0); a1 = fmaf(wv.y, hr[1], a1);
        a2 = fmaf(wv.y, hr[2], a2); a3 = fmaf(wv.y, hr[3], a3);
        hr += 34;
        a0 = fmaf(wv.z, hr[0], a0); a1 = fmaf(wv.z, hr[1], a1);
        a2 = fmaf(wv.z, hr[2], a2); a3 = fmaf(wv.z, hr[3], a3);
        hr += 34;
        a0 = fmaf(wv.w, hr[0], a0); a1 = fmaf(wv.w, hr[1], a1);
        a2 = fmaf(wv.w, hr[2], a2); a3 = fmaf(wv.w, hr[3], a3);
      }
      float s = sb[256 + oc], bb = sb[384 + oc];
      float v0 = fmaxf(fmaf(a0, s, bb), 0.f);
      float v1 = fmaxf(fmaf(a1, s, bb), 0.f);
      float v2 = fmaxf(fmaf(a2, s, bb), 0.f);
      float v3 = fmaxf(fmaf(a3, s, bb), 0.f);
      float mv = fmaxf(fmaxf(v0, v1), fmaxf(v2, v3));
      atomicMax(&hm[oc], __float_as_int(mv));   // values >= 0: int order == float order
    }
    __syncthreads();

    if (tid < 128)
      outF[(((size_t)b * 128 + tid) << 10) + m] = __int_as_float(hm[tid]);
    __syncthreads();
  }
}

// ---------------------------------------------------------------------------
extern "C" void kernel_launch(void* const* d_in, const int* in_sizes, int n_in,
                              void* d_out, int out_size, void* d_ws, size_t ws_size,
                              hipStream_t stream)
{
  if (n_in < 11) return;
  const float* xyz   = (const float*)d_in[0];
  const float* feats = (const float*)d_in[1];
  const float* W1 = (const float*)d_in[2];
  const float* s1 = (const float*)d_in[3];
  const float* b1 = (const float*)d_in[4];
  const float* W2 = (const float*)d_in[5];
  const float* s2 = (const float*)d_in[6];
  const float* b2 = (const float*)d_in[7];
  const float* W3 = (const float*)d_in[8];
  const float* s3 = (const float*)d_in[9];
  const float* b3 = (const float*)d_in[10];
  float* out = (float*)d_out;

  // ws layout: [0, gridBytes) sorted-point scratch for fps_grid; featsT after.
  size_t gridBytes = (size_t)BATCH * NPTS * sizeof(float4);   // 1 MB
  size_t needT = (size_t)BATCH * NPTS * 64 * sizeof(float);
  float* featsT = nullptr;
  if (ws_size >= gridBytes + needT)
    featsT = (float*)((char*)d_ws + gridBytes);

  if (ws_size >= gridBytes)
    fps_grid<<<BATCH, FPS_T, 0, stream>>>(xyz, out, (float4*)d_ws);
  else
    fps_single<<<BATCH, FPS_T, 0, stream>>>(xyz, out);

  if (featsT) transpose_kernel<<<BATCH * 256, 256, 0, stream>>>(feats, featsT);
  mlp_kernel<<<512, 1024, 0, stream>>>(xyz, feats, featsT, out,
                                       W1, s1, b1, W2, s2, b2, W3, s3, b3,
                                       out + BATCH * NPOINT * 3);
}